// Round 10
// baseline (1308.684 us; speedup 1.0000x reference)
//
#include <hip/hip_runtime.h>
#include <hip/hip_fp16.h>

#define B_ 512
#define T_ 512
#define H_ 64
#define K_ 4

// ws layout:
//   wht  f16 [K*3][8][64][8]  @ 0        (98304 B)  chunk-transposed W_h
//   wit  f16 [3][8][64][8]    @ 98304    (24576 B)  chunk-transposed W_i  (contiguous with wht)
//   flag int                  @ 123136
//   xh16 f16 [B*T*H]          @ 131072   (33554432 B)
#define WS_WIT_OFF   98304
#define WS_FLAG_OFF  123136
#define WS_XH_OFF    131072

// dynamic LDS: Wh [0,98304) ; Wi [98304,122880) ; h scratch @122880
//   h scratch: [chain c:2][buf:2][64 halves] -> c*256 + buf*128
#define LDS_HSC_OFF  122880
#define LDS_TOTAL    123392
#define STAGE_U4     7680      // 122880 / 16  (Wh + Wi in one pass)

typedef _Float16 half2_t __attribute__((ext_vector_type(2)));

union Q { uint4 u; half2_t h[4]; };  // 16 B = 4 packed half2

__device__ __forceinline__ float fdot2f(half2_t a, half2_t b, float c) {
#if __has_builtin(__builtin_amdgcn_fdot2)
    return __builtin_amdgcn_fdot2(a, b, c, false);
#else
    return fmaf((float)a[0], (float)b[0], fmaf((float)a[1], (float)b[1], c));
#endif
}

__device__ __forceinline__ half2_t pkh2(float a, float b) {
    return __builtin_bit_cast(half2_t, __builtin_amdgcn_cvt_pkrtz(a, b));
}

// Detect whether mask buffer is 1-byte bools or int32 0/1 (little-endian).
__global__ void detect_mask_kernel(const unsigned char* __restrict__ mb, int* __restrict__ flag) {
    __shared__ int cnt;
    if (threadIdx.x == 0) cnt = 0;
    __syncthreads();
    int c = 0;
    for (int i = threadIdx.x; i < 4096; i += blockDim.x)
        if ((i & 3) != 0 && mb[i] != 0) c++;
    atomicAdd(&cnt, c);
    __syncthreads();
    if (threadIdx.x == 0) *flag = (cnt > 0) ? 1 : 0;  // 1 => uint8 bools, 0 => int32
}

// Weights -> f16 chunk-transposed: dst u4 index (mat*8 + j/8)*64 + i
__global__ void convert_weights_kernel(const float* __restrict__ Whr, const float* __restrict__ Whz,
                                       const float* __restrict__ Whn, const float* __restrict__ Wir,
                                       const float* __restrict__ Wiz, const float* __restrict__ Win,
                                       __half* __restrict__ wht, __half* __restrict__ wit) {
    int idx = blockIdx.x * 256 + threadIdx.x;
    if (idx < K_ * 3 * H_ * H_) {
        int mat = idx >> 12;            // k*3+g
        int i   = (idx >> 6) & 63;
        int j   = idx & 63;
        int k   = mat / 3, g = mat - 3 * k;
        const float* src = (g == 0) ? Whr : (g == 1) ? Whz : Whn;
        wht[((mat * 8 + (j >> 3)) * 64 + i) * 8 + (j & 7)] = __float2half(src[(k * H_ + i) * H_ + j]);
    }
    if (idx < 3 * H_ * H_) {
        int g = idx >> 12;
        int i = (idx >> 6) & 63;
        int j = idx & 63;
        const float* src = (g == 0) ? Wir : (g == 1) ? Wiz : Win;
        wit[((g * 8 + (j >> 3)) * 64 + i) * 8 + (j & 7)] = __float2half(src[i * H_ + j]);
    }
}

// x f32 -> packed f16
__global__ void convert_x_kernel(const float* __restrict__ xf, __half* __restrict__ xh) {
    size_t i = (size_t)blockIdx.x * 256 + threadIdx.x;
    if (i >= (size_t)B_ * T_ * H_ / 8) return;
    const float4* p = (const float4*)xf + 2 * i;
    float4 a = p[0], b = p[1];
    Q o;
    o.h[0] = pkh2(a.x, a.y);
    o.h[1] = pkh2(a.z, a.w);
    o.h[2] = pkh2(b.x, b.y);
    o.h[3] = pkh2(b.z, b.w);
    ((uint4*)xh)[i] = o.u;
}

// Sequential GRU: ONE WAVE PER BLOCK, TWO CHAINS PER WAVE (A = 2*blk, B = 2*blk+1).
// The two chains' instruction streams interleave in straight-line code, so one
// chain's latency stalls (LDS drains, 32-deep fdot2 accumulation, exp chain,
// h round trip, shuffle-reduce) are filled by the other chain's issue.
// All weights in LDS (120 KB, 1 block/CU, staged once); W_i read once per step
// serves both chains. lane = output row i; per-chain full-row matvecs via fdot2.
__global__ __launch_bounds__(64, 1)
void gru_seq5(const __half* __restrict__ xh16, const int* __restrict__ ctx,
              const unsigned char* __restrict__ maskb, const int* __restrict__ flagp,
              const __half* __restrict__ wht,
              const float* __restrict__ b_ir, const float* __restrict__ b_iz,
              const float* __restrict__ b_in, const float* __restrict__ b_hr,
              const float* __restrict__ b_hz, const float* __restrict__ b_hn,
              const float* __restrict__ Wo_w, const float* __restrict__ Wo_b,
              float* __restrict__ out) {
    extern __shared__ __align__(16) char smem[];
    uint4* sw  = (uint4*)smem;          // Wh image (6144 u4)
    uint4* swi = sw + 6144;             // Wi image (1536 u4)

    const int lane = threadIdx.x;       // 0..63 (one wave per block)
    const int bA   = blockIdx.x * 2;
    const int bB   = bA + 1;

    // ---- stage Wh + Wi (contiguous, 122880 B) into LDS, once ----
    {
        const uint4* gsrc = (const uint4*)wht;
#pragma unroll 1
        for (int i = lane; i < STAGE_U4; i += 64) sw[i] = gsrc[i];
    }
    __syncthreads();

    const int flag   = *flagp;
    const int mshift = flag ? 0 : 2;
    const int btA0   = bA * T_;
    const int btB0   = bB * T_;

    // biases: input (3) + all 4 experts' hidden (12) + output head (4)
    const float bir = b_ir[lane], biz = b_iz[lane], bin = b_in[lane];
    const float bhr0 = b_hr[lane],       bhz0 = b_hz[lane],       bhn0 = b_hn[lane];
    const float bhr1 = b_hr[64 + lane],  bhz1 = b_hz[64 + lane],  bhn1 = b_hn[64 + lane];
    const float bhr2 = b_hr[128 + lane], bhz2 = b_hz[128 + lane], bhn2 = b_hn[128 + lane];
    const float bhr3 = b_hr[192 + lane], bhz3 = b_hz[192 + lane], bhn3 = b_hn[192 + lane];
    const float wo0 = Wo_w[lane], wo1 = Wo_w[64 + lane];
    const float wob0 = Wo_b[0], wob1 = Wo_b[1];

    float hregA = 0.0f, hregB = 0.0f;
    Q hqA[8], hqB[8];
#pragma unroll
    for (int q = 0; q < 8; q++) { hqA[q].u = make_uint4(0u,0u,0u,0u); hqB[q].u = make_uint4(0u,0u,0u,0u); }

    // per-chain h scratch (double-buffered)
    __half* hscA = (__half*)(smem + LDS_HSC_OFF);
    __half* hscB = (__half*)(smem + LDS_HSC_OFF + 256);

    int   kcA = __builtin_amdgcn_readfirstlane(ctx[btA0]);
    int   kcB = __builtin_amdgcn_readfirstlane(ctx[btB0]);
    float mcA = maskb[(size_t)btA0 << mshift] ? 1.0f : 0.0f;
    float mcB = maskb[(size_t)btB0 << mshift] ? 1.0f : 0.0f;

    float* outA = out + (size_t)bA * T_ * 2;
    float* outB = out + (size_t)bB * T_ * 2;

#pragma unroll 1
    for (int t = 0; t < T_; t++) {
        const int tn = (t + 1 < T_) ? (t + 1) : t;

        // ---- issue x(t) loads for both chains (uniform-address f16 rows);
        //      consumed by ip ~600 cycles later -> L2 latency hidden ----
        Q xA[8], xB[8];
        {
            const uint4* xpA = (const uint4*)(xh16 + (size_t)(btA0 + t) * H_);
            const uint4* xpB = (const uint4*)(xh16 + (size_t)(btB0 + t) * H_);
#pragma unroll
            for (int q = 0; q < 8; q++) { xA[q].u = xpA[q]; xB[q].u = xpB[q]; }
        }
        // next-step ctx/mask (h-independent)
        int           knA = ctx[btA0 + tn],  knB = ctx[btB0 + tn];
        unsigned char mnA = maskb[(size_t)(btA0 + tn) << mshift];
        unsigned char mnB = maskb[(size_t)(btB0 + tn) << mshift];

        // ---- hidden matvec A (W_h[kcA] from LDS, compiler-pipelined chunks) ----
        float shrA = 0.f, shzA = 0.f, shnA = 0.f;
        {
            const uint4* whp = sw + kcA * 1536 + lane;
#pragma unroll
            for (int q = 0; q < 8; q++) {
                Q wr, wz, wn;
                wr.u = whp[q * 64];
                wz.u = whp[512 + q * 64];
                wn.u = whp[1024 + q * 64];
#pragma unroll
                for (int p = 0; p < 4; p++) {
                    shrA = fdot2f(wr.h[p], hqA[q].h[p], shrA);
                    shzA = fdot2f(wz.h[p], hqA[q].h[p], shzA);
                    shnA = fdot2f(wn.h[p], hqA[q].h[p], shnA);
                }
            }
        }
        // ---- hidden matvec B ----
        float shrB = 0.f, shzB = 0.f, shnB = 0.f;
        {
            const uint4* whp = sw + kcB * 1536 + lane;
#pragma unroll
            for (int q = 0; q < 8; q++) {
                Q wr, wz, wn;
                wr.u = whp[q * 64];
                wz.u = whp[512 + q * 64];
                wn.u = whp[1024 + q * 64];
#pragma unroll
                for (int p = 0; p < 4; p++) {
                    shrB = fdot2f(wr.h[p], hqB[q].h[p], shrB);
                    shzB = fdot2f(wz.h[p], hqB[q].h[p], shzB);
                    shnB = fdot2f(wn.h[p], hqB[q].h[p], shnB);
                }
            }
        }

        // ---- input projections: W_i read once (LDS), serves both chains ----
        float sirA = bir, sizA = biz, sinA = bin;
        float sirB = bir, sizB = biz, sinB = bin;
#pragma unroll
        for (int q = 0; q < 8; q++) {
            Q wr, wz, wn;
            wr.u = swi[q * 64 + lane];
            wz.u = swi[512 + q * 64 + lane];
            wn.u = swi[1024 + q * 64 + lane];
#pragma unroll
            for (int p = 0; p < 4; p++) {
                sirA = fdot2f(wr.h[p], xA[q].h[p], sirA);
                sizA = fdot2f(wz.h[p], xA[q].h[p], sizA);
                sinA = fdot2f(wn.h[p], xA[q].h[p], sinA);
                sirB = fdot2f(wr.h[p], xB[q].h[p], sirB);
                sizB = fdot2f(wz.h[p], xB[q].h[p], sizB);
                sinB = fdot2f(wn.h[p], xB[q].h[p], sinB);
            }
        }

        // expert biases (wave-uniform selects)
        const float bhrA = (kcA == 0) ? bhr0 : (kcA == 1) ? bhr1 : (kcA == 2) ? bhr2 : bhr3;
        const float bhzA = (kcA == 0) ? bhz0 : (kcA == 1) ? bhz1 : (kcA == 2) ? bhz2 : bhz3;
        const float bhnA = (kcA == 0) ? bhn0 : (kcA == 1) ? bhn1 : (kcA == 2) ? bhn2 : bhn3;
        const float bhrB = (kcB == 0) ? bhr0 : (kcB == 1) ? bhr1 : (kcB == 2) ? bhr2 : bhr3;
        const float bhzB = (kcB == 0) ? bhz0 : (kcB == 1) ? bhz1 : (kcB == 2) ? bhz2 : bhz3;
        const float bhnB = (kcB == 0) ? bhn0 : (kcB == 1) ? bhn1 : (kcB == 2) ? bhn2 : bhn3;

        // ---- epilogues (independent -> interleave, transcendentals overlap) ----
        const float arA = sirA + shrA + bhrA, azA = sizA + shzA + bhzA;
        const float arB = sirB + shrB + bhrB, azB = sizB + shzB + bhzB;
        const float rA = 1.0f / (1.0f + __expf(-arA));
        const float rB = 1.0f / (1.0f + __expf(-arB));
        const float zA = 1.0f / (1.0f + __expf(-azA));
        const float zB = 1.0f / (1.0f + __expf(-azB));
        const float aA = sinA + rA * (shnA + bhnA);
        const float aB = sinB + rB * (shnB + bhnB);
        const float nA = 2.0f / (1.0f + __expf(-2.0f * aA)) - 1.0f;
        const float nB = 2.0f / (1.0f + __expf(-2.0f * aB)) - 1.0f;
        float hnA = nA + zA * (hregA - nA);
        float hnB = nB + zB * (hregB - nB);
        hnA = (mcA > 0.5f) ? hnA : hregA;
        hnB = (mcB > 0.5f) ? hnB : hregB;
        hregA = hnA; hregB = hnB;

        // ---- h broadcast round trips (double-buffered, same-wave in-order DS) ----
        __half* hbA = hscA + ((t & 1) << 6);
        __half* hbB = hscB + ((t & 1) << 6);
        hbA[lane] = __float2half(hnA);
        hbB[lane] = __float2half(hnB);
        __builtin_amdgcn_wave_barrier();
        {
            const uint4* hpA = (const uint4*)hbA;
            const uint4* hpB = (const uint4*)hbB;
#pragma unroll
            for (int q = 0; q < 8; q++) { hqA[q].u = hpA[q]; hqB[q].u = hpB[q]; }
        }
        __builtin_amdgcn_wave_barrier();

        // ---- logits (two independent shuffle chains interleave) ----
        {
            float l0A = hnA * wo0, l1A = hnA * wo1;
            float l0B = hnB * wo0, l1B = hnB * wo1;
#pragma unroll
            for (int m = 32; m >= 1; m >>= 1) {
                l0A += __shfl_xor(l0A, m, 64);
                l1A += __shfl_xor(l1A, m, 64);
                l0B += __shfl_xor(l0B, m, 64);
                l1B += __shfl_xor(l1B, m, 64);
            }
            if (lane == 0) {
                *(float2*)(outA + t * 2) = make_float2(l0A + wob0, l1A + wob1);
                *(float2*)(outB + t * 2) = make_float2(l0B + wob0, l1B + wob1);
            }
        }

        kcA = __builtin_amdgcn_readfirstlane(knA);
        kcB = __builtin_amdgcn_readfirstlane(knB);
        mcA = mnA ? 1.0f : 0.0f;
        mcB = mnB ? 1.0f : 0.0f;
    }
}

extern "C" void kernel_launch(void* const* d_in, const int* in_sizes, int n_in,
                              void* d_out, int out_size, void* d_ws, size_t ws_size,
                              hipStream_t stream) {
    const float* x    = (const float*)d_in[0];
    const int*   ctx  = (const int*)d_in[1];
    const void*  mask = d_in[2];
    const float* W_ir = (const float*)d_in[3];
    const float* W_iz = (const float*)d_in[4];
    const float* W_in = (const float*)d_in[5];
    const float* bir  = (const float*)d_in[6];
    const float* biz  = (const float*)d_in[7];
    const float* bin  = (const float*)d_in[8];
    const float* W_hr = (const float*)d_in[9];
    const float* W_hz = (const float*)d_in[10];
    const float* W_hn = (const float*)d_in[11];
    const float* bhr  = (const float*)d_in[12];
    const float* bhz  = (const float*)d_in[13];
    const float* bhn  = (const float*)d_in[14];
    const float* Wo_w = (const float*)d_in[15];
    const float* Wo_b = (const float*)d_in[16];

    char* ws = (char*)d_ws;
    __half* wht  = (__half*)ws;
    __half* wit  = (__half*)(ws + WS_WIT_OFF);
    int*    flag = (int*)(ws + WS_FLAG_OFF);
    __half* xh16 = (__half*)(ws + WS_XH_OFF);

    detect_mask_kernel<<<1, 256, 0, stream>>>((const unsigned char*)mask, flag);
    convert_weights_kernel<<<192, 256, 0, stream>>>(W_hr, W_hz, W_hn, W_ir, W_iz, W_in,
                                                    wht, wit);
    convert_x_kernel<<<8192, 256, 0, stream>>>(x, xh16);

    (void)hipFuncSetAttribute((const void*)gru_seq5,
                              hipFuncAttributeMaxDynamicSharedMemorySize, LDS_TOTAL);
    gru_seq5<<<B_ / 2, 64, LDS_TOTAL, stream>>>(
        xh16, ctx, (const unsigned char*)mask, flag, wht,
        bir, biz, bin, bhr, bhz, bhn, Wo_w, Wo_b, (float*)d_out);
}

// Round 11
// 672.544 us; speedup vs baseline: 1.9459x; 1.9459x over previous
//
#include <hip/hip_runtime.h>
#include <hip/hip_fp16.h>

#define B_ 512
#define T_ 512
#define H_ 64
#define K_ 4

// ws layout:
//   wht  f16 [K*3][8][64][8]  @ 0        (98304 B)  chunk-transposed W_h
//   wit  f16 [3][8][64][8]    @ 98304    (24576 B)  chunk-transposed W_i (contiguous)
//   flag int                  @ 123136
//   xh16 f16 [B*T*H]          @ 131072   (33554432 B)
#define WS_WIT_OFF   98304
#define WS_FLAG_OFF  123136
#define WS_XH_OFF    131072

// dynamic LDS: Wh [0,98304) ; Wi [98304,122880) ; h scratch @122880
//   h scratch: [wave:2][buf:2][64 halves]  -> wave*256 + buf*128 bytes
#define LDS_HSC_OFF  122880
#define LDS_TOTAL    123392
#define STAGE_U4     7680      // 122880 / 16 (Wh + Wi staged in one pass)

typedef _Float16 half2_t __attribute__((ext_vector_type(2)));

union Q { uint4 u; half2_t h[4]; };  // 16 B = 4 packed half2

__device__ __forceinline__ float fdot2f(half2_t a, half2_t b, float c) {
#if __has_builtin(__builtin_amdgcn_fdot2)
    return __builtin_amdgcn_fdot2(a, b, c, false);
#else
    return fmaf((float)a[0], (float)b[0], fmaf((float)a[1], (float)b[1], c));
#endif
}

__device__ __forceinline__ half2_t pkh2(float a, float b) {
    return __builtin_bit_cast(half2_t, __builtin_amdgcn_cvt_pkrtz(a, b));
}

// Detect whether mask buffer is 1-byte bools or int32 0/1 (little-endian).
__global__ void detect_mask_kernel(const unsigned char* __restrict__ mb, int* __restrict__ flag) {
    __shared__ int cnt;
    if (threadIdx.x == 0) cnt = 0;
    __syncthreads();
    int c = 0;
    for (int i = threadIdx.x; i < 4096; i += blockDim.x)
        if ((i & 3) != 0 && mb[i] != 0) c++;
    atomicAdd(&cnt, c);
    __syncthreads();
    if (threadIdx.x == 0) *flag = (cnt > 0) ? 1 : 0;  // 1 => uint8 bools, 0 => int32
}

// Weights -> f16 chunk-transposed: dst u4 index (mat*8 + j/8)*64 + i
__global__ void convert_weights_kernel(const float* __restrict__ Whr, const float* __restrict__ Whz,
                                       const float* __restrict__ Whn, const float* __restrict__ Wir,
                                       const float* __restrict__ Wiz, const float* __restrict__ Win,
                                       __half* __restrict__ wht, __half* __restrict__ wit) {
    int idx = blockIdx.x * 256 + threadIdx.x;
    if (idx < K_ * 3 * H_ * H_) {
        int mat = idx >> 12;            // k*3+g
        int i   = (idx >> 6) & 63;
        int j   = idx & 63;
        int k   = mat / 3, g = mat - 3 * k;
        const float* src = (g == 0) ? Whr : (g == 1) ? Whz : Whn;
        wht[((mat * 8 + (j >> 3)) * 64 + i) * 8 + (j & 7)] = __float2half(src[(k * H_ + i) * H_ + j]);
    }
    if (idx < 3 * H_ * H_) {
        int g = idx >> 12;
        int i = (idx >> 6) & 63;
        int j = idx & 63;
        const float* src = (g == 0) ? Wir : (g == 1) ? Wiz : Win;
        wit[((g * 8 + (j >> 3)) * 64 + i) * 8 + (j & 7)] = __float2half(src[i * H_ + j]);
    }
}

// x f32 -> packed f16
__global__ void convert_x_kernel(const float* __restrict__ xf, __half* __restrict__ xh) {
    size_t i = (size_t)blockIdx.x * 256 + threadIdx.x;
    if (i >= (size_t)B_ * T_ * H_ / 8) return;
    const float4* p = (const float4*)xf + 2 * i;
    float4 a = p[0], b = p[1];
    Q o;
    o.h[0] = pkh2(a.x, a.y);
    o.h[1] = pkh2(a.z, a.w);
    o.h[2] = pkh2(b.x, b.y);
    o.h[3] = pkh2(b.z, b.w);
    ((uint4*)xh)[i] = o.u;
}

// One iteration of the recurrence. WCUR: W_h[k(t)] already in registers.
// WNXT: destination buffer for W_h[k(t+1)] prefetch (24 back-to-back
// ds_read_b128 with no same-iteration consumer -> they drain in the
// epilogue/round-trip shadow instead of gating the matvec).
#define STEP(TT, WCUR, WNXT, BUF)                                              \
{                                                                              \
    const int tt = (TT);                                                       \
    const int tn = (tt + 1 < T_) ? tt + 1 : T_ - 1;                            \
    /* x(t) row (uniform address, f16-packed) */                               \
    Q xq[8];                                                                   \
    { const uint4* xp = (const uint4*)(xh16 + (size_t)(bt0 + tt) * H_);        \
      _Pragma("unroll") for (int q = 0; q < 8; q++) xq[q].u = xp[q]; }         \
    /* hidden matvec on register-resident WCUR, 4-way accumulator trees */     \
    float ar4[4] = {0,0,0,0}, az4[4] = {0,0,0,0}, an4[4] = {0,0,0,0};          \
    _Pragma("unroll") for (int q = 0; q < 8; q++) {                            \
        _Pragma("unroll") for (int p = 0; p < 4; p++) {                        \
            ar4[q >> 1] = fdot2f(WCUR[q].h[p],      hq[q].h[p], ar4[q >> 1]);  \
            az4[q >> 1] = fdot2f(WCUR[8 + q].h[p],  hq[q].h[p], az4[q >> 1]);  \
            an4[q >> 1] = fdot2f(WCUR[16 + q].h[p], hq[q].h[p], an4[q >> 1]);  \
        }                                                                      \
    }                                                                          \
    const float shr = (ar4[0] + ar4[1]) + (ar4[2] + ar4[3]);                   \
    const float shz = (az4[0] + az4[1]) + (az4[2] + az4[3]);                   \
    const float shn = (an4[0] + an4[1]) + (an4[2] + an4[3]);                   \
    /* input projection: W_i from LDS (h-independent) */                       \
    float sir = bir, siz = biz, sin_ = bin;                                    \
    _Pragma("unroll") for (int q = 0; q < 8; q++) {                            \
        Q wr, wz, wn;                                                          \
        wr.u = swi[q * 64 + lane];                                             \
        wz.u = swi[512 + q * 64 + lane];                                       \
        wn.u = swi[1024 + q * 64 + lane];                                      \
        _Pragma("unroll") for (int p = 0; p < 4; p++) {                        \
            sir  = fdot2f(wr.h[p], xq[q].h[p], sir);                           \
            siz  = fdot2f(wz.h[p], xq[q].h[p], siz);                           \
            sin_ = fdot2f(wn.h[p], xq[q].h[p], sin_);                          \
        }                                                                      \
    }                                                                          \
    /* t+1 prefetches: ctx, mask, expert biases, and W_h[kn] -> WNXT */        \
    const int kn = __builtin_amdgcn_readfirstlane(ctx[bt0 + tn]);              \
    const unsigned char mn = maskb[(size_t)(bt0 + tn) << mshift];              \
    const float bhr_n = b_hr[kn * H_ + lane];                                  \
    const float bhz_n = b_hz[kn * H_ + lane];                                  \
    const float bhn_n = b_hn[kn * H_ + lane];                                  \
    { const uint4* wp = sw + kn * 1536 + lane;                                 \
      _Pragma("unroll") for (int q = 0; q < 8; q++) {                          \
        WNXT[q].u      = wp[q * 64];                                           \
        WNXT[8 + q].u  = wp[512 + q * 64];                                     \
        WNXT[16 + q].u = wp[1024 + q * 64];                                    \
      } }                                                                      \
    /* epilogue (in-lane) */                                                   \
    const float arv = sir + shr + bhr_c;                                       \
    const float azv = siz + shz + bhz_c;                                       \
    const float rr  = 1.0f / (1.0f + __expf(-arv));                            \
    const float zz  = 1.0f / (1.0f + __expf(-azv));                            \
    const float aa  = sin_ + rr * (shn + bhn_c);                               \
    const float nn2 = 2.0f / (1.0f + __expf(-2.0f * aa)) - 1.0f;               \
    float hnew = nn2 + zz * (hreg - nn2);                                      \
    hnew = (mc > 0.5f) ? hnew : hreg;                                          \
    hreg = hnew;                                                               \
    /* same-wave h broadcast round trip (double-buffered) */                   \
    { __half* hb = hsc + ((BUF) << 6);                                         \
      hb[lane] = __float2half(hnew);                                           \
      __builtin_amdgcn_wave_barrier();                                         \
      const uint4* hp = (const uint4*)hb;                                      \
      _Pragma("unroll") for (int q = 0; q < 8; q++) hq[q].u = hp[q];           \
      __builtin_amdgcn_wave_barrier(); }                                       \
    /* logits (in the round-trip / W-prefetch shadow) */                       \
    { float l0 = hnew * wo0, l1 = hnew * wo1;                                  \
      _Pragma("unroll") for (int m = 32; m >= 1; m >>= 1) {                    \
          l0 += __shfl_xor(l0, m, 64);                                         \
          l1 += __shfl_xor(l1, m, 64);                                         \
      }                                                                        \
      if (lane == 0) *(float2*)(outp + tt * 2) = make_float2(l0 + wob0, l1 + wob1); } \
    bhr_c = bhr_n; bhz_c = bhz_n; bhn_c = bhn_n;                               \
    mc = mn ? 1.0f : 0.0f;                                                     \
}

// Sequential GRU: 256 blocks x 128 threads = 2 independent waves (2 chains)
// sharing one 120 KB LDS weight image. No block barriers in the loop.
// W_h[k(t)] lives in a 96-VGPR named register buffer, double-buffered across
// an unroll-by-2 loop so the 24 prefetch ds_read_b128 issue back-to-back a
// full step ahead of use (fixes R8/R9's serialized DS latency).
__global__ __launch_bounds__(128, 1)
void gru_seq6(const __half* __restrict__ xh16, const int* __restrict__ ctx,
              const unsigned char* __restrict__ maskb, const int* __restrict__ flagp,
              const __half* __restrict__ wht,
              const float* __restrict__ b_ir, const float* __restrict__ b_iz,
              const float* __restrict__ b_in, const float* __restrict__ b_hr,
              const float* __restrict__ b_hz, const float* __restrict__ b_hn,
              const float* __restrict__ Wo_w, const float* __restrict__ Wo_b,
              float* __restrict__ out) {
    extern __shared__ __align__(16) char smem[];
    uint4* sw  = (uint4*)smem;          // Wh image (6144 u4)
    uint4* swi = sw + 6144;             // Wi image (1536 u4)

    const int tid  = threadIdx.x;
    const int lane = tid & 63;
    const int wv   = tid >> 6;          // 0,1
    const int b    = blockIdx.x * 2 + wv;

    // ---- stage Wh + Wi (contiguous, 122880 B) into LDS, once ----
    {
        const uint4* gsrc = (const uint4*)wht;
#pragma unroll 1
        for (int i = tid; i < STAGE_U4; i += 128) sw[i] = gsrc[i];
    }
    __syncthreads();

    const int flag   = *flagp;
    const int mshift = flag ? 0 : 2;
    const int bt0    = b * T_;

    const float bir = b_ir[lane], biz = b_iz[lane], bin = b_in[lane];
    const float wo0 = Wo_w[lane], wo1 = Wo_w[64 + lane];
    const float wob0 = Wo_b[0], wob1 = Wo_b[1];

    __half* hsc = (__half*)(smem + LDS_HSC_OFF + (wv << 8));
    float*  outp = out + (size_t)b * T_ * 2;

    float hreg = 0.0f;
    Q hq[8];
#pragma unroll
    for (int q = 0; q < 8; q++) hq[q].u = make_uint4(0u, 0u, 0u, 0u);

    // ---- prologue: k(0), mask(0), expert biases, W_h[k0] -> wA ----
    Q wA[24], wB[24];
    const int k0 = __builtin_amdgcn_readfirstlane(ctx[bt0]);
    float mc = maskb[(size_t)bt0 << mshift] ? 1.0f : 0.0f;
    float bhr_c = b_hr[k0 * H_ + lane];
    float bhz_c = b_hz[k0 * H_ + lane];
    float bhn_c = b_hn[k0 * H_ + lane];
    {
        const uint4* wp = sw + k0 * 1536 + lane;
#pragma unroll
        for (int q = 0; q < 8; q++) {
            wA[q].u      = wp[q * 64];
            wA[8 + q].u  = wp[512 + q * 64];
            wA[16 + q].u = wp[1024 + q * 64];
        }
    }

#pragma unroll 1
    for (int t = 0; t < T_; t += 2) {
        STEP(t,     wA, wB, 0)
        STEP(t + 1, wB, wA, 1)
    }
}

extern "C" void kernel_launch(void* const* d_in, const int* in_sizes, int n_in,
                              void* d_out, int out_size, void* d_ws, size_t ws_size,
                              hipStream_t stream) {
    const float* x    = (const float*)d_in[0];
    const int*   ctx  = (const int*)d_in[1];
    const void*  mask = d_in[2];
    const float* W_ir = (const float*)d_in[3];
    const float* W_iz = (const float*)d_in[4];
    const float* W_in = (const float*)d_in[5];
    const float* bir  = (const float*)d_in[6];
    const float* biz  = (const float*)d_in[7];
    const float* bin  = (const float*)d_in[8];
    const float* W_hr = (const float*)d_in[9];
    const float* W_hz = (const float*)d_in[10];
    const float* W_hn = (const float*)d_in[11];
    const float* bhr  = (const float*)d_in[12];
    const float* bhz  = (const float*)d_in[13];
    const float* bhn  = (const float*)d_in[14];
    const float* Wo_w = (const float*)d_in[15];
    const float* Wo_b = (const float*)d_in[16];

    char* ws = (char*)d_ws;
    __half* wht  = (__half*)ws;
    __half* wit  = (__half*)(ws + WS_WIT_OFF);
    int*    flag = (int*)(ws + WS_FLAG_OFF);
    __half* xh16 = (__half*)(ws + WS_XH_OFF);

    detect_mask_kernel<<<1, 256, 0, stream>>>((const unsigned char*)mask, flag);
    convert_weights_kernel<<<192, 256, 0, stream>>>(W_hr, W_hz, W_hn, W_ir, W_iz, W_in,
                                                    wht, wit);
    convert_x_kernel<<<8192, 256, 0, stream>>>(x, xh16);

    (void)hipFuncSetAttribute((const void*)gru_seq6,
                              hipFuncAttributeMaxDynamicSharedMemorySize, LDS_TOTAL);
    gru_seq6<<<B_ / 2, 128, LDS_TOTAL, stream>>>(
        xh16, ctx, (const unsigned char*)mask, flag, wht,
        bir, biz, bin, bhr, bhz, bhn, Wo_w, Wo_b, (float*)d_out);
}